// Round 4
// baseline (4631.580 us; speedup 1.0000x reference)
//
#include <hip/hip_runtime.h>
#include <hip/hip_bf16.h>

typedef __bf16 bf16_t;
typedef bf16_t bf16x4 __attribute__((ext_vector_type(4)));
typedef bf16_t bf16x8 __attribute__((ext_vector_type(8)));
typedef float f32x4 __attribute__((ext_vector_type(4)));

static constexpr int N_NODES = 50000;
static constexpr int N_EDGES = 1600000;
static constexpr int FIN = 1280;
static constexpr int HD = 128;
static constexpr int NG = 64;
// 0.5/sqrt(pi)/sqrt(128)
static constexpr float TP_NORM_F = 0.0249338908f;

// src-tile / dst-block bucketing for L2-resident gathers
static constexpr int TSH = 13;                 // src tile = 8192 nodes = 2 MB of h (fits 4MB XCD L2)
static constexpr int TILES = 7;                // ceil(50000/8192)
static constexpr int DB = 782;                 // ceil(50000/64) dst blocks of 64 nodes
static constexpr int NBUCK = TILES * DB;       // 5474

// ---- packed: weight prep (768 blocks) + edge histogram pass (6250 blocks).
// prep zeroes pbuf/gcnt. cnt/bcnt zeroed by preceding memset.
__global__ __launch_bounds__(256) void k_prep_hist(const float* __restrict__ lin_w,
                                                   const float* __restrict__ tp1,
                                                   const float* __restrict__ tp2,
                                                   bf16_t* __restrict__ WtL,
                                                   bf16_t* __restrict__ Wt1,
                                                   bf16_t* __restrict__ Wt2,
                                                   float* __restrict__ pbuf,
                                                   float* __restrict__ gcnt,
                                                   const int* __restrict__ srcE,
                                                   const int* __restrict__ dstE,
                                                   int* __restrict__ cnt,
                                                   int* __restrict__ bcnt,
                                                   int* __restrict__ pos) {
  const int PREP_BLOCKS = 768;  // covers FIN*HD + 2*HD*HD = 196608 exactly
  if (blockIdx.x < PREP_BLOCKS) {
    int idx = blockIdx.x * 256 + threadIdx.x;
    const int totL = FIN * HD;      // 163840
    const int tot1 = HD * HD;       // 16384
    if (idx < totL) {
      int k = idx >> 7, n = idx & 127;
      WtL[n * FIN + k] = (bf16_t)lin_w[idx];
    } else if (idx < totL + tot1) {
      int j = idx - totL;
      int k = j >> 7, n = j & 127;
      Wt1[n * HD + k] = (bf16_t)(tp1[j] * TP_NORM_F);
    } else {
      int j = idx - totL - tot1;
      int k = j >> 7, n = j & 127;
      Wt2[n * HD + k] = (bf16_t)(tp2[j] * TP_NORM_F);
    }
    if (idx < NG * HD) pbuf[idx] = 0.f;
    if (idx < NG) gcnt[idx] = 0.f;
  } else {
    int e = (blockIdx.x - PREP_BLOCKS) * 256 + threadIdx.x;
    if (e < N_EDGES) {
      int s = srcE[e], d = dstE[e];
      atomicAdd(&cnt[d], 1);                       // in-degree (mean denominator)
      int key = (s >> TSH) * DB + (d >> 6);        // (srcTile, dstBlock)
      pos[e] = atomicAdd(&bcnt[key], 1);
    }
  }
}

// ---- hierarchical scan over bcnt[NBUCK] -> boff
__global__ __launch_bounds__(256) void k_scan1(const int* __restrict__ cnt, int* __restrict__ bsum, int n) {
  __shared__ int s[256];
  int t = threadIdx.x;
  int i = blockIdx.x * 256 + t;
  s[t] = (i < n) ? cnt[i] : 0;
  __syncthreads();
  for (int d = 128; d > 0; d >>= 1) {
    if (t < d) s[t] += s[t + d];
    __syncthreads();
  }
  if (t == 0) bsum[blockIdx.x] = s[0];
}

__global__ __launch_bounds__(256) void k_scan2(int* __restrict__ bsum, int nb) {
  __shared__ int s[256];
  int t = threadIdx.x;
  int v = (t < nb) ? bsum[t] : 0;
  s[t] = v;
  __syncthreads();
  for (int d = 1; d < 256; d <<= 1) {
    int x = (t >= d) ? s[t - d] : 0;
    __syncthreads();
    s[t] += x;
    __syncthreads();
  }
  if (t < nb) bsum[t] = s[t] - v;
  if (t == 255) bsum[nb] = s[255];
}

__global__ __launch_bounds__(256) void k_scan3(const int* __restrict__ cnt, const int* __restrict__ bsum,
                                               int* __restrict__ off, int n) {
  __shared__ int s[256];
  int t = threadIdx.x;
  int i = blockIdx.x * 256 + t;
  int v = (i < n) ? cnt[i] : 0;
  s[t] = v;
  __syncthreads();
  for (int d = 1; d < 256; d <<= 1) {
    int x = (t >= d) ? s[t - d] : 0;
    __syncthreads();
    s[t] += x;
    __syncthreads();
  }
  if (i < n) off[i] = bsum[blockIdx.x] + s[t] - v;
  if (i == n - 1) off[n] = bsum[blockIdx.x] + s[t];
}

// ---- packed: lin GEMM (1563 blocks, 32x128 tile, K=1280) + bucket scatter (6250 blocks).
// epack = (dstLocal6 << 16) | src16  (src < 65536, dstLocal < 64)
__global__ __launch_bounds__(256) void k_lin_fill(const float* __restrict__ A,
                                                  const bf16_t* __restrict__ Bt,
                                                  const float* __restrict__ bias,
                                                  bf16_t* __restrict__ C,
                                                  const int* __restrict__ srcE,
                                                  const int* __restrict__ dstE,
                                                  const int* __restrict__ boff,
                                                  const int* __restrict__ pos,
                                                  int* __restrict__ epack) {
  __shared__ bf16_t As[32 * 64];
  __shared__ bf16_t Bs[128 * 64];
  const int GB = (N_NODES + 31) / 32;  // 1563
  if (blockIdx.x >= GB) {
    int e = (blockIdx.x - GB) * 256 + threadIdx.x;
    if (e < N_EDGES) {
      int s = srcE[e], d = dstE[e];
      int key = (s >> TSH) * DB + (d >> 6);
      epack[boff[key] + pos[e]] = ((d & 63) << 16) | s;
    }
    return;
  }
  const int M = N_NODES, K = FIN;
  const int t = threadIdx.x;
  const int wid = t >> 6;
  const int lane = t & 63;
  const int wn = wid * 32;
  const int l15 = lane & 15;
  const int quad = lane >> 4;
  const int rowBase = blockIdx.x * 32;

  f32x4 acc[2][2];
#pragma unroll
  for (int i = 0; i < 2; ++i)
#pragma unroll
    for (int j = 0; j < 2; ++j) {
      f32x4 z = {0.f, 0.f, 0.f, 0.f};
      acc[i][j] = z;
    }

  for (int k0 = 0; k0 < K; k0 += 64) {
#pragma unroll
    for (int i = 0; i < 2; ++i) {
      int idx = t + i * 256;
      int row = idx >> 4;
      int col4 = idx & 15;
      int gr = rowBase + row;
      float4 v = make_float4(0.f, 0.f, 0.f, 0.f);
      if (gr < M) v = *(const float4*)(A + (size_t)gr * K + k0 + col4 * 4);
      bf16x4 w;
      w[0] = (bf16_t)v.x; w[1] = (bf16_t)v.y; w[2] = (bf16_t)v.z; w[3] = (bf16_t)v.w;
      int c = col4 >> 1;
      int off = row * 64 + ((c ^ (row & 7)) << 3) + ((col4 & 1) << 2);
      *(bf16x4*)&As[off] = w;
    }
#pragma unroll
    for (int i = 0; i < 4; ++i) {
      int idx = t + i * 256;
      int row = idx >> 3;
      int c = idx & 7;
      bf16x8 v = *(const bf16x8*)(Bt + (size_t)row * K + k0 + c * 8);
      int off = row * 64 + ((c ^ (row & 7)) << 3);
      *(bf16x8*)&Bs[off] = v;
    }
    __syncthreads();
#pragma unroll
    for (int kk = 0; kk < 2; ++kk) {
      bf16x8 af[2], bfr[2];
      int k8 = kk * 4 + quad;
#pragma unroll
      for (int mi = 0; mi < 2; ++mi) {
        int row = mi * 16 + l15;
        af[mi] = *(const bf16x8*)&As[row * 64 + ((k8 ^ (row & 7)) << 3)];
      }
#pragma unroll
      for (int ni = 0; ni < 2; ++ni) {
        int row = wn + ni * 16 + l15;
        bfr[ni] = *(const bf16x8*)&Bs[row * 64 + ((k8 ^ (row & 7)) << 3)];
      }
#pragma unroll
      for (int mi = 0; mi < 2; ++mi)
#pragma unroll
        for (int ni = 0; ni < 2; ++ni)
          acc[mi][ni] = __builtin_amdgcn_mfma_f32_16x16x32_bf16(af[mi], bfr[ni], acc[mi][ni], 0, 0, 0);
    }
    __syncthreads();
  }

#pragma unroll
  for (int mi = 0; mi < 2; ++mi) {
#pragma unroll
    for (int ni = 0; ni < 2; ++ni) {
      int col = wn + ni * 16 + l15;
      float bv = bias[col];
#pragma unroll
      for (int r = 0; r < 4; ++r) {
        int row = mi * 16 + quad * 4 + r;
        int gr = rowBase + row;
        if (gr < M) {
          float v = acc[mi][ni][r] + bv;
          v = fmaxf(v, 0.f);
          C[(size_t)gr * HD + col] = (bf16_t)v;
        }
      }
    }
  }
}

// ---- bucketed mean-aggregate: one block per dst-block of 64 nodes, fp32 acc in LDS.
// Sweeps src-tiles in order so concurrent blocks gather from the same 2MB h window
// (L2-resident). LDS adds use per-row rotation (+4*dl) to spread banks.
__global__ __launch_bounds__(256) void k_agg_bucket(const bf16_t* __restrict__ h,
                                                    const int* __restrict__ epack,
                                                    const int* __restrict__ boff,
                                                    const int* __restrict__ cnt,
                                                    bf16_t* __restrict__ agg, int n) {
  __shared__ float accS[64 * 128];  // 32 KB
  const int t = threadIdx.x;
  const int wid = t >> 6;
  const int lane = t & 63;
  const int grp = wid * 4 + (lane >> 4);  // 0..15
  const int fl = lane & 15;
  const int db = blockIdx.x;

#pragma unroll
  for (int i = 0; i < 32; ++i) accS[t + i * 256] = 0.f;
  __syncthreads();

  const bf16_t* hp = h + fl * 8;
  for (int tt = 0; tt < TILES; ++tt) {
    int lo = boff[tt * DB + db];
    int hi = boff[tt * DB + db + 1];
    int i = lo + grp;
    for (; i + 16 < hi; i += 32) {
      int p0 = epack[i];
      int p1 = epack[i + 16];
      int s0 = p0 & 0xFFFF, dl0 = p0 >> 16;
      int s1 = p1 & 0xFFFF, dl1 = p1 >> 16;
      bf16x8 v0 = *(const bf16x8*)(hp + (size_t)s0 * HD);
      bf16x8 v1 = *(const bf16x8*)(hp + (size_t)s1 * HD);
#pragma unroll
      for (int j = 0; j < 8; ++j)
        atomicAdd(&accS[dl0 * 128 + ((fl * 8 + j + dl0 * 4) & 127)], (float)v0[j]);
#pragma unroll
      for (int j = 0; j < 8; ++j)
        atomicAdd(&accS[dl1 * 128 + ((fl * 8 + j + dl1 * 4) & 127)], (float)v1[j]);
    }
    if (i < hi) {
      int p0 = epack[i];
      int s0 = p0 & 0xFFFF, dl0 = p0 >> 16;
      bf16x8 v0 = *(const bf16x8*)(hp + (size_t)s0 * HD);
#pragma unroll
      for (int j = 0; j < 8; ++j)
        atomicAdd(&accS[dl0 * 128 + ((fl * 8 + j + dl0 * 4) & 127)], (float)v0[j]);
    }
  }
  __syncthreads();

  // write out: 64 rows, 16 groups -> 4 rows per group
#pragma unroll
  for (int it = 0; it < 4; ++it) {
    int r = it * 16 + grp;
    int node = db * 64 + r;
    if (node < n) {
      int c = cnt[node];
      float inv = (c > 0) ? 1.f / (float)c : 0.f;
      bf16x8 o;
#pragma unroll
      for (int j = 0; j < 8; ++j)
        o[j] = (bf16_t)(accS[r * 128 + ((fl * 8 + j + r * 4) & 127)] * inv);
      *(bf16x8*)(agg + (size_t)node * HD + fl * 8) = o;
    }
  }
}

// ---- MFMA GEMM (conv1/conv2): C[M x 128] = relu(A[M x 128] @ Bt^T)
__global__ __launch_bounds__(256) void k_gemm32(const bf16_t* __restrict__ A,
                                                const bf16_t* __restrict__ Bt,
                                                bf16_t* __restrict__ C,
                                                int M) {
  __shared__ bf16_t As[32 * 64];
  __shared__ bf16_t Bs[128 * 64];
  const int K = HD;
  const int t = threadIdx.x;
  const int wid = t >> 6;
  const int lane = t & 63;
  const int wn = wid * 32;
  const int l15 = lane & 15;
  const int quad = lane >> 4;
  const int rowBase = blockIdx.x * 32;

  f32x4 acc[2][2];
#pragma unroll
  for (int i = 0; i < 2; ++i)
#pragma unroll
    for (int j = 0; j < 2; ++j) {
      f32x4 z = {0.f, 0.f, 0.f, 0.f};
      acc[i][j] = z;
    }

  for (int k0 = 0; k0 < K; k0 += 64) {
    {
      int row = t >> 3;
      int c = t & 7;
      int gr = rowBase + row;
      bf16x8 v = {};
      if (gr < M) v = *(const bf16x8*)(A + (size_t)gr * K + k0 + c * 8);
      int off = row * 64 + ((c ^ (row & 7)) << 3);
      *(bf16x8*)&As[off] = v;
    }
#pragma unroll
    for (int i = 0; i < 4; ++i) {
      int idx = t + i * 256;
      int row = idx >> 3;
      int c = idx & 7;
      bf16x8 v = *(const bf16x8*)(Bt + (size_t)row * K + k0 + c * 8);
      int off = row * 64 + ((c ^ (row & 7)) << 3);
      *(bf16x8*)&Bs[off] = v;
    }
    __syncthreads();
#pragma unroll
    for (int kk = 0; kk < 2; ++kk) {
      bf16x8 af[2], bfr[2];
      int k8 = kk * 4 + quad;
#pragma unroll
      for (int mi = 0; mi < 2; ++mi) {
        int row = mi * 16 + l15;
        af[mi] = *(const bf16x8*)&As[row * 64 + ((k8 ^ (row & 7)) << 3)];
      }
#pragma unroll
      for (int ni = 0; ni < 2; ++ni) {
        int row = wn + ni * 16 + l15;
        bfr[ni] = *(const bf16x8*)&Bs[row * 64 + ((k8 ^ (row & 7)) << 3)];
      }
#pragma unroll
      for (int mi = 0; mi < 2; ++mi)
#pragma unroll
        for (int ni = 0; ni < 2; ++ni)
          acc[mi][ni] = __builtin_amdgcn_mfma_f32_16x16x32_bf16(af[mi], bfr[ni], acc[mi][ni], 0, 0, 0);
    }
    __syncthreads();
  }

#pragma unroll
  for (int mi = 0; mi < 2; ++mi) {
#pragma unroll
    for (int ni = 0; ni < 2; ++ni) {
      int col = wn + ni * 16 + l15;
#pragma unroll
      for (int r = 0; r < 4; ++r) {
        int row = mi * 16 + quad * 4 + r;
        int gr = rowBase + row;
        if (gr < M) {
          float v = fmaxf(acc[mi][ni][r], 0.f);
          C[(size_t)gr * HD + col] = (bf16_t)v;
        }
      }
    }
  }
}

// ---- pool: 64-row chunks
__global__ __launch_bounds__(128) void k_pool(const bf16_t* __restrict__ agg, const int* __restrict__ batch,
                                              float* __restrict__ p, float* __restrict__ gcnt, int n) {
  int base = blockIdx.x * 64;
  if (base >= n) return;
  int t = threadIdx.x;
  int end = min(base + 64, n);
  float acc = 0.f;
  int curg = batch[base];
  int runStart = base;
  for (int i = base; i < end; ++i) {
    int g = batch[i];
    if (g != curg) {
      atomicAdd(&p[curg * HD + t], acc);
      if (t == 0) atomicAdd(&gcnt[curg], (float)(i - runStart));
      acc = 0.f; curg = g; runStart = i;
    }
    acc += (float)agg[(size_t)i * HD + t];
  }
  atomicAdd(&p[curg * HD + t], acc);
  if (t == 0) atomicAdd(&gcnt[curg], (float)(end - runStart));
}

// ---- head
__global__ __launch_bounds__(128) void k_head(const float* __restrict__ p, const float* __restrict__ gcnt,
                                              const float* __restrict__ w3,
                                              const float* __restrict__ c1w, const float* __restrict__ c1b,
                                              const float* __restrict__ c2w, const float* __restrict__ c2b,
                                              const float* __restrict__ c3w, const float* __restrict__ c3b,
                                              float* __restrict__ out) {
  __shared__ float sa[128], sb[128];
  int g = blockIdx.x, t = threadIdx.x;
  float inv = 1.f / fmaxf(gcnt[g], 1.f);
  sa[t] = p[g * HD + t] * inv;
  __syncthreads();
  float z = 0.f;
  for (int k = 0; k < HD; ++k) z += sa[k] * w3[k * HD + t];
  z *= TP_NORM_F;
  out[128 + g * HD + t] = z;
  sb[t] = z;
  __syncthreads();
  float o1 = c1b[t];
  for (int k = 0; k < HD; ++k) o1 += sb[k] * c1w[k * HD + t];
  o1 = fmaxf(o1, 0.f);
  __syncthreads();
  sa[t] = o1;
  __syncthreads();
  float o2 = c2b[t];
  for (int k = 0; k < HD; ++k) o2 += sa[k] * c2w[k * HD + t];
  o2 = fmaxf(o2, 0.f);
  __syncthreads();
  sb[t] = o2;
  __syncthreads();
  if (t < 2) {
    float o = c3b[t];
    for (int k = 0; k < HD; ++k) o += sb[k] * c3w[k * 2 + t];
    out[g * 2 + t] = o;
  }
}

extern "C" void kernel_launch(void* const* d_in, const int* in_sizes, int n_in,
                              void* d_out, int out_size, void* d_ws, size_t ws_size,
                              hipStream_t stream) {
  const float* x = (const float*)d_in[0];
  const int* eidx = (const int*)d_in[2];
  const int* src = eidx;
  const int* dst = eidx + N_EDGES;
  const int* batch = (const int*)d_in[3];
  const float* lin_w = (const float*)d_in[4];
  const float* lin_b = (const float*)d_in[5];
  const float* tp_w1 = (const float*)d_in[6];
  const float* tp_w2 = (const float*)d_in[7];
  const float* tp_w3 = (const float*)d_in[8];
  const float* c1w = (const float*)d_in[9];
  const float* c1b = (const float*)d_in[10];
  const float* c2w = (const float*)d_in[11];
  const float* c2b = (const float*)d_in[12];
  const float* c3w = (const float*)d_in[13];
  const float* c3b = (const float*)d_in[14];
  float* out = (float*)d_out;
  (void)in_sizes; (void)n_in; (void)out_size; (void)ws_size;

  uintptr_t wp = (uintptr_t)d_ws;
  auto alloc = [&](size_t bytes) -> void* {
    uintptr_t a = (wp + 255) & ~(uintptr_t)255;
    wp = a + bytes;
    return (void*)a;
  };
  bf16_t* WtL  = (bf16_t*)alloc(sizeof(bf16_t) * (size_t)HD * FIN);
  bf16_t* Wt1  = (bf16_t*)alloc(sizeof(bf16_t) * (size_t)HD * HD);
  bf16_t* Wt2  = (bf16_t*)alloc(sizeof(bf16_t) * (size_t)HD * HD);
  bf16_t* h    = (bf16_t*)alloc(sizeof(bf16_t) * (size_t)50048 * HD);
  bf16_t* agg  = (bf16_t*)alloc(sizeof(bf16_t) * (size_t)50048 * HD);
  int*    zero = (int*)alloc(sizeof(int) * (N_NODES + NBUCK));  // cnt + bcnt, one memset
  int*    cnt  = zero;
  int*    bcnt = zero + N_NODES;
  int*    bsum = (int*)alloc(sizeof(int) * 256);
  int*    boff = (int*)alloc(sizeof(int) * (NBUCK + 1));
  int*    pos  = (int*)alloc(sizeof(int) * N_EDGES);
  int*    epack= (int*)alloc(sizeof(int) * N_EDGES);
  float*  pbuf = (float*)alloc(sizeof(float) * NG * HD);
  float*  gcnt = (float*)alloc(sizeof(float) * NG);

  hipMemsetAsync(zero, 0, sizeof(int) * (N_NODES + NBUCK), stream);

  const int edgeBlocks = (N_EDGES + 255) / 256;  // 6250
  k_prep_hist<<<768 + edgeBlocks, 256, 0, stream>>>(lin_w, tp_w1, tp_w2, WtL, Wt1, Wt2,
                                                    pbuf, gcnt, src, dst, cnt, bcnt, pos);

  const int nScanBlocks = (NBUCK + 255) / 256;  // 22
  k_scan1<<<nScanBlocks, 256, 0, stream>>>(bcnt, bsum, NBUCK);
  k_scan2<<<1, 256, 0, stream>>>(bsum, nScanBlocks);
  k_scan3<<<nScanBlocks, 256, 0, stream>>>(bcnt, bsum, boff, NBUCK);

  const int gblocks = (N_NODES + 31) / 32;   // 1563
  // packed: h0 = relu(x @ lin_w + b)  ||  epack bucket scatter
  k_lin_fill<<<gblocks + edgeBlocks, 256, 0, stream>>>(x, WtL, lin_b, h, src, dst, boff, pos, epack);

  // conv1
  k_agg_bucket<<<DB, 256, 0, stream>>>(h, epack, boff, cnt, agg, N_NODES);
  k_gemm32<<<gblocks, 256, 0, stream>>>(agg, Wt1, h, N_NODES);
  // conv2
  k_agg_bucket<<<DB, 256, 0, stream>>>(h, epack, boff, cnt, agg, N_NODES);
  k_gemm32<<<gblocks, 256, 0, stream>>>(agg, Wt2, h, N_NODES);
  // conv3 aggregation only (W3 folded into head)
  k_agg_bucket<<<DB, 256, 0, stream>>>(h, epack, boff, cnt, agg, N_NODES);

  k_pool<<<(N_NODES + 63) / 64, 128, 0, stream>>>(agg, batch, pbuf, gcnt, N_NODES);
  k_head<<<NG, 128, 0, stream>>>(pbuf, gcnt, tp_w3, c1w, c1b, c2w, c2b, c3w, c3b, out);
}

// Round 5
// 718.971 us; speedup vs baseline: 6.4420x; 6.4420x over previous
//
#include <hip/hip_runtime.h>
#include <hip/hip_bf16.h>

typedef __bf16 bf16_t;
typedef bf16_t bf16x4 __attribute__((ext_vector_type(4)));
typedef bf16_t bf16x8 __attribute__((ext_vector_type(8)));
typedef float f32x4 __attribute__((ext_vector_type(4)));

static constexpr int N_NODES = 50000;
static constexpr int N_EDGES = 1600000;
static constexpr int FIN = 1280;
static constexpr int HD = 128;
static constexpr int NG = 64;
// 0.5/sqrt(pi)/sqrt(128)
static constexpr float TP_NORM_F = 0.0249338908f;

// dst-major bucketing with fine src tiles: key = dst*TPN + (src>>TILE_SH).
// Per-node edge lists stay contiguous (dst-major) but are ordered by src tile,
// so concurrent waves walking their lists front-to-back gather from the same
// ~256KB window of h (L2-resident), no structural change to the gather kernel.
static constexpr int TILE_SH = 10;             // src tile = 1024 nodes = 256 KB of h
static constexpr int TPN = 49;                 // tiles per node = ceil(50000/1024)
static constexpr int NBUCK = N_NODES * TPN;    // 2,450,000

// ---- packed: weight prep (768 blocks) + edge histogram pass (6250 blocks).
__global__ __launch_bounds__(256) void k_prep_hist(const float* __restrict__ lin_w,
                                                   const float* __restrict__ tp1,
                                                   const float* __restrict__ tp2,
                                                   bf16_t* __restrict__ WtL,
                                                   bf16_t* __restrict__ Wt1,
                                                   bf16_t* __restrict__ Wt2,
                                                   float* __restrict__ pbuf,
                                                   float* __restrict__ gcnt,
                                                   const int* __restrict__ srcE,
                                                   const int* __restrict__ dstE,
                                                   int* __restrict__ bcnt,
                                                   int* __restrict__ pos) {
  const int PREP_BLOCKS = 768;  // covers FIN*HD + 2*HD*HD = 196608 exactly
  if (blockIdx.x < PREP_BLOCKS) {
    int idx = blockIdx.x * 256 + threadIdx.x;
    const int totL = FIN * HD;      // 163840
    const int tot1 = HD * HD;       // 16384
    if (idx < totL) {
      int k = idx >> 7, n = idx & 127;
      WtL[n * FIN + k] = (bf16_t)lin_w[idx];
    } else if (idx < totL + tot1) {
      int j = idx - totL;
      int k = j >> 7, n = j & 127;
      Wt1[n * HD + k] = (bf16_t)(tp1[j] * TP_NORM_F);
    } else {
      int j = idx - totL - tot1;
      int k = j >> 7, n = j & 127;
      Wt2[n * HD + k] = (bf16_t)(tp2[j] * TP_NORM_F);
    }
    if (idx < NG * HD) pbuf[idx] = 0.f;
    if (idx < NG) gcnt[idx] = 0.f;
  } else {
    int e = (blockIdx.x - PREP_BLOCKS) * 256 + threadIdx.x;
    if (e < N_EDGES) {
      int s = srcE[e], d = dstE[e];
      int key = d * TPN + (s >> TILE_SH);
      pos[e] = atomicAdd(&bcnt[key], 1);
    }
  }
}

// ---- generic scan pieces (3-level chain for 2.45M buckets)
__global__ __launch_bounds__(256) void k_scan1(const int* __restrict__ cnt, int* __restrict__ bsum, int n) {
  __shared__ int s[256];
  int t = threadIdx.x;
  int i = blockIdx.x * 256 + t;
  s[t] = (i < n) ? cnt[i] : 0;
  __syncthreads();
  for (int d = 128; d > 0; d >>= 1) {
    if (t < d) s[t] += s[t + d];
    __syncthreads();
  }
  if (t == 0) bsum[blockIdx.x] = s[0];
}

__global__ __launch_bounds__(256) void k_scan2(int* __restrict__ bsum, int nb) {
  __shared__ int s[256];
  int t = threadIdx.x;
  int v = (t < nb) ? bsum[t] : 0;
  s[t] = v;
  __syncthreads();
  for (int d = 1; d < 256; d <<= 1) {
    int x = (t >= d) ? s[t - d] : 0;
    __syncthreads();
    s[t] += x;
    __syncthreads();
  }
  if (t < nb) bsum[t] = s[t] - v;  // exclusive
  if (t == 255) bsum[nb] = s[255]; // total
}

// off[i] = bsum[blockIdx] + exclusive_local(cnt); off[n] = total
__global__ __launch_bounds__(256) void k_scan3(const int* __restrict__ cnt, const int* __restrict__ bsum,
                                               int* __restrict__ off, int n) {
  __shared__ int s[256];
  int t = threadIdx.x;
  int i = blockIdx.x * 256 + t;
  int v = (i < n) ? cnt[i] : 0;
  s[t] = v;
  __syncthreads();
  for (int d = 1; d < 256; d <<= 1) {
    int x = (t >= d) ? s[t - d] : 0;
    __syncthreads();
    s[t] += x;
    __syncthreads();
  }
  if (i < n) off[i] = bsum[blockIdx.x] + s[t] - v;
  if (i == n - 1) off[n] = bsum[blockIdx.x] + s[t];
}

// ---- packed: lin GEMM (1563 blocks, 32x128 tile, K=1280) + bucket scatter (6250 blocks).
__global__ __launch_bounds__(256) void k_lin_fill(const float* __restrict__ A,
                                                  const bf16_t* __restrict__ Bt,
                                                  const float* __restrict__ bias,
                                                  bf16_t* __restrict__ C,
                                                  const int* __restrict__ srcE,
                                                  const int* __restrict__ dstE,
                                                  const int* __restrict__ boff,
                                                  const int* __restrict__ pos,
                                                  int* __restrict__ ssrc) {
  __shared__ bf16_t As[32 * 64];
  __shared__ bf16_t Bs[128 * 64];
  const int GB = (N_NODES + 31) / 32;  // 1563
  if (blockIdx.x >= GB) {
    int e = (blockIdx.x - GB) * 256 + threadIdx.x;
    if (e < N_EDGES) {
      int s = srcE[e], d = dstE[e];
      int key = d * TPN + (s >> TILE_SH);
      ssrc[boff[key] + pos[e]] = s;
    }
    return;
  }
  const int M = N_NODES, K = FIN;
  const int t = threadIdx.x;
  const int wid = t >> 6;
  const int lane = t & 63;
  const int wn = wid * 32;
  const int l15 = lane & 15;
  const int quad = lane >> 4;
  const int rowBase = blockIdx.x * 32;

  f32x4 acc[2][2];
#pragma unroll
  for (int i = 0; i < 2; ++i)
#pragma unroll
    for (int j = 0; j < 2; ++j) {
      f32x4 z = {0.f, 0.f, 0.f, 0.f};
      acc[i][j] = z;
    }

  for (int k0 = 0; k0 < K; k0 += 64) {
#pragma unroll
    for (int i = 0; i < 2; ++i) {
      int idx = t + i * 256;
      int row = idx >> 4;
      int col4 = idx & 15;
      int gr = rowBase + row;
      float4 v = make_float4(0.f, 0.f, 0.f, 0.f);
      if (gr < M) v = *(const float4*)(A + (size_t)gr * K + k0 + col4 * 4);
      bf16x4 w;
      w[0] = (bf16_t)v.x; w[1] = (bf16_t)v.y; w[2] = (bf16_t)v.z; w[3] = (bf16_t)v.w;
      int c = col4 >> 1;
      int off = row * 64 + ((c ^ (row & 7)) << 3) + ((col4 & 1) << 2);
      *(bf16x4*)&As[off] = w;
    }
#pragma unroll
    for (int i = 0; i < 4; ++i) {
      int idx = t + i * 256;
      int row = idx >> 3;
      int c = idx & 7;
      bf16x8 v = *(const bf16x8*)(Bt + (size_t)row * K + k0 + c * 8);
      int off = row * 64 + ((c ^ (row & 7)) << 3);
      *(bf16x8*)&Bs[off] = v;
    }
    __syncthreads();
#pragma unroll
    for (int kk = 0; kk < 2; ++kk) {
      bf16x8 af[2], bfr[2];
      int k8 = kk * 4 + quad;
#pragma unroll
      for (int mi = 0; mi < 2; ++mi) {
        int row = mi * 16 + l15;
        af[mi] = *(const bf16x8*)&As[row * 64 + ((k8 ^ (row & 7)) << 3)];
      }
#pragma unroll
      for (int ni = 0; ni < 2; ++ni) {
        int row = wn + ni * 16 + l15;
        bfr[ni] = *(const bf16x8*)&Bs[row * 64 + ((k8 ^ (row & 7)) << 3)];
      }
#pragma unroll
      for (int mi = 0; mi < 2; ++mi)
#pragma unroll
        for (int ni = 0; ni < 2; ++ni)
          acc[mi][ni] = __builtin_amdgcn_mfma_f32_16x16x32_bf16(af[mi], bfr[ni], acc[mi][ni], 0, 0, 0);
    }
    __syncthreads();
  }

#pragma unroll
  for (int mi = 0; mi < 2; ++mi) {
#pragma unroll
    for (int ni = 0; ni < 2; ++ni) {
      int col = wn + ni * 16 + l15;
      float bv = bias[col];
#pragma unroll
      for (int r = 0; r < 4; ++r) {
        int row = mi * 16 + quad * 4 + r;
        int gr = rowBase + row;
        if (gr < M) {
          float v = acc[mi][ni][r] + bv;
          v = fmaxf(v, 0.f);
          C[(size_t)gr * HD + col] = (bf16_t)v;
        }
      }
    }
  }
}

// ---- fused conv: aggregate 32 nodes into LDS (swizzled) + 32x128x128 MFMA GEMM.
// Node edge list: [boff[node*TPN], boff[node*TPN+TPN]) - contiguous, src-tile sorted.
__global__ __launch_bounds__(256) void k_conv_fused(const bf16_t* __restrict__ hin,
                                                    const int* __restrict__ ssrc,
                                                    const int* __restrict__ boff,
                                                    const bf16_t* __restrict__ Bt,
                                                    bf16_t* __restrict__ hout, int n) {
  __shared__ bf16_t As[32 * 128];
  __shared__ bf16_t Bs[128 * 128];
  const int t = threadIdx.x;
  const int wid = t >> 6;
  const int lane = t & 63;
  const int g = lane >> 4;
  const int fl = lane & 15;
  const int rowBase = blockIdx.x * 32;

  // stage B: 128x128 bf16 = 2048 chunks of 8; 8 per thread
#pragma unroll
  for (int i = 0; i < 8; ++i) {
    int idx = t + i * 256;
    int row = idx >> 4;   // 0..127
    int cc = idx & 15;    // chunk in row
    bf16x8 v = *(const bf16x8*)(Bt + (size_t)row * HD + cc * 8);
    int hh = cc >> 3, c = cc & 7;
    int ob = (row * 2 + hh) * 64 + ((c ^ (row & 7)) << 3);
    *(bf16x8*)&Bs[ob] = v;
  }

  // aggregate 8 nodes per wave into As
  const bf16_t* hp = hin + fl * 8;
  for (int i = 0; i < 8; ++i) {
    int localRow = wid * 8 + i;
    int node = rowBase + localRow;
    if (node >= n) break;
    int b = boff[node * TPN], e = boff[node * TPN + TPN];
    int deg = e - b;
    int d64 = min(deg, 64);
    int idxr = (lane < deg) ? ssrc[b + lane] : 0;
    float acc[8];
#pragma unroll
    for (int j = 0; j < 8; ++j) acc[j] = 0.f;

    int j0 = 0;
    for (; j0 + 32 <= d64; j0 += 32) {
      int s[8];
#pragma unroll
      for (int k = 0; k < 8; ++k) s[k] = __shfl(idxr, j0 + 4 * k + g);
      bf16x8 v[8];
#pragma unroll
      for (int k = 0; k < 8; ++k) v[k] = *(const bf16x8*)(hp + (size_t)s[k] * HD);
#pragma unroll
      for (int k = 0; k < 8; ++k)
#pragma unroll
        for (int jj = 0; jj < 8; ++jj) acc[jj] += (float)v[k][jj];
    }
    for (; j0 + 8 <= d64; j0 += 8) {
      int s0 = __shfl(idxr, j0 + g);
      int s1 = __shfl(idxr, j0 + 4 + g);
      bf16x8 v0 = *(const bf16x8*)(hp + (size_t)s0 * HD);
      bf16x8 v1 = *(const bf16x8*)(hp + (size_t)s1 * HD);
#pragma unroll
      for (int jj = 0; jj < 8; ++jj) acc[jj] += (float)v0[jj] + (float)v1[jj];
    }
    if (j0 + 4 <= d64) {
      int s0 = __shfl(idxr, j0 + g);
      bf16x8 v0 = *(const bf16x8*)(hp + (size_t)s0 * HD);
#pragma unroll
      for (int jj = 0; jj < 8; ++jj) acc[jj] += (float)v0[jj];
      j0 += 4;
    }
    if (j0 + g < d64) {
      int s0 = __shfl(idxr, j0 + g);
      bf16x8 v0 = *(const bf16x8*)(hp + (size_t)s0 * HD);
#pragma unroll
      for (int jj = 0; jj < 8; ++jj) acc[jj] += (float)v0[jj];
    }
    for (int ii = b + 64; ii + g < e; ii += 4) {
      int s0 = ssrc[ii + g];
      bf16x8 v0 = *(const bf16x8*)(hp + (size_t)s0 * HD);
#pragma unroll
      for (int jj = 0; jj < 8; ++jj) acc[jj] += (float)v0[jj];
    }
#pragma unroll
    for (int j = 0; j < 8; ++j) {
      acc[j] += __shfl_xor(acc[j], 16);
      acc[j] += __shfl_xor(acc[j], 32);
    }
    if (g == 0) {
      float inv = (e > b) ? 1.f / (float)(e - b) : 0.f;
      bf16x8 o;
#pragma unroll
      for (int j = 0; j < 8; ++j) o[j] = (bf16_t)(acc[j] * inv);
      int hh = fl >> 3, c = fl & 7;
      int oa = (localRow * 2 + hh) * 64 + ((c ^ (localRow & 7)) << 3);
      *(bf16x8*)&As[oa] = o;
    }
  }
  __syncthreads();

  // GEMM: 32x128 outputs, K=128 in LDS
  const int wn = wid * 32;
  const int l15 = lane & 15;
  const int quad = lane >> 4;
  f32x4 acc[2][2];
#pragma unroll
  for (int i = 0; i < 2; ++i)
#pragma unroll
    for (int j = 0; j < 2; ++j) {
      f32x4 z = {0.f, 0.f, 0.f, 0.f};
      acc[i][j] = z;
    }
#pragma unroll
  for (int kk = 0; kk < 4; ++kk) {
    int k16 = kk * 4 + quad;  // 0..15
    int hh = k16 >> 3, c = k16 & 7;
    bf16x8 af[2], bfr[2];
#pragma unroll
    for (int mi = 0; mi < 2; ++mi) {
      int row = mi * 16 + l15;
      af[mi] = *(const bf16x8*)&As[(row * 2 + hh) * 64 + ((c ^ (row & 7)) << 3)];
    }
#pragma unroll
    for (int ni = 0; ni < 2; ++ni) {
      int row = wn + ni * 16 + l15;
      bfr[ni] = *(const bf16x8*)&Bs[(row * 2 + hh) * 64 + ((c ^ (row & 7)) << 3)];
    }
#pragma unroll
    for (int mi = 0; mi < 2; ++mi)
#pragma unroll
      for (int ni = 0; ni < 2; ++ni)
        acc[mi][ni] = __builtin_amdgcn_mfma_f32_16x16x32_bf16(af[mi], bfr[ni], acc[mi][ni], 0, 0, 0);
  }

#pragma unroll
  for (int mi = 0; mi < 2; ++mi) {
#pragma unroll
    for (int ni = 0; ni < 2; ++ni) {
      int col = wn + ni * 16 + l15;
#pragma unroll
      for (int r = 0; r < 4; ++r) {
        int row = mi * 16 + quad * 4 + r;
        int gr = rowBase + row;
        if (gr < n) {
          float v = fmaxf(acc[mi][ni][r], 0.f);
          hout[(size_t)gr * HD + col] = (bf16_t)v;
        }
      }
    }
  }
}

// ---- standalone mean-aggregate (conv3 -> pool path)
__global__ __launch_bounds__(256) void k_aggregate(const bf16_t* __restrict__ h,
                                                   const int* __restrict__ ssrc,
                                                   const int* __restrict__ boff,
                                                   bf16_t* __restrict__ agg, int n) {
  int node = blockIdx.x * 4 + (threadIdx.x >> 6);
  if (node >= n) return;
  int lane = threadIdx.x & 63;
  int g = lane >> 4;
  int fl = lane & 15;
  int b = boff[node * TPN], e = boff[node * TPN + TPN];
  int deg = e - b;
  int d64 = min(deg, 64);
  int idxr = (lane < deg) ? ssrc[b + lane] : 0;
  float acc[8];
#pragma unroll
  for (int j = 0; j < 8; ++j) acc[j] = 0.f;
  const bf16_t* hp = h + fl * 8;

  int j0 = 0;
  for (; j0 + 32 <= d64; j0 += 32) {
    int s[8];
#pragma unroll
    for (int k = 0; k < 8; ++k) s[k] = __shfl(idxr, j0 + 4 * k + g);
    bf16x8 v[8];
#pragma unroll
    for (int k = 0; k < 8; ++k) v[k] = *(const bf16x8*)(hp + (size_t)s[k] * HD);
#pragma unroll
    for (int k = 0; k < 8; ++k)
#pragma unroll
      for (int jj = 0; jj < 8; ++jj) acc[jj] += (float)v[k][jj];
  }
  for (; j0 + 8 <= d64; j0 += 8) {
    int s0 = __shfl(idxr, j0 + g);
    int s1 = __shfl(idxr, j0 + 4 + g);
    bf16x8 v0 = *(const bf16x8*)(hp + (size_t)s0 * HD);
    bf16x8 v1 = *(const bf16x8*)(hp + (size_t)s1 * HD);
#pragma unroll
    for (int jj = 0; jj < 8; ++jj) acc[jj] += (float)v0[jj] + (float)v1[jj];
  }
  if (j0 + 4 <= d64) {
    int s0 = __shfl(idxr, j0 + g);
    bf16x8 v0 = *(const bf16x8*)(hp + (size_t)s0 * HD);
#pragma unroll
    for (int jj = 0; jj < 8; ++jj) acc[jj] += (float)v0[jj];
    j0 += 4;
  }
  if (j0 + g < d64) {
    int s0 = __shfl(idxr, j0 + g);
    bf16x8 v0 = *(const bf16x8*)(hp + (size_t)s0 * HD);
#pragma unroll
    for (int jj = 0; jj < 8; ++jj) acc[jj] += (float)v0[jj];
  }
  for (int i = b + 64; i + g < e; i += 4) {
    int s0 = ssrc[i + g];
    bf16x8 v0 = *(const bf16x8*)(hp + (size_t)s0 * HD);
#pragma unroll
    for (int jj = 0; jj < 8; ++jj) acc[jj] += (float)v0[jj];
  }

#pragma unroll
  for (int j = 0; j < 8; ++j) {
    acc[j] += __shfl_xor(acc[j], 16);
    acc[j] += __shfl_xor(acc[j], 32);
  }
  if (g == 0) {
    float inv = (e > b) ? 1.f / (float)(e - b) : 0.f;
    bf16x8 o;
#pragma unroll
    for (int j = 0; j < 8; ++j) o[j] = (bf16_t)(acc[j] * inv);
    *(bf16x8*)(agg + (size_t)node * HD + fl * 8) = o;
  }
}

// ---- pool: 64-row chunks
__global__ __launch_bounds__(128) void k_pool(const bf16_t* __restrict__ agg, const int* __restrict__ batch,
                                              float* __restrict__ p, float* __restrict__ gcnt, int n) {
  int base = blockIdx.x * 64;
  if (base >= n) return;
  int t = threadIdx.x;
  int end = min(base + 64, n);
  float acc = 0.f;
  int curg = batch[base];
  int runStart = base;
  for (int i = base; i < end; ++i) {
    int g = batch[i];
    if (g != curg) {
      atomicAdd(&p[curg * HD + t], acc);
      if (t == 0) atomicAdd(&gcnt[curg], (float)(i - runStart));
      acc = 0.f; curg = g; runStart = i;
    }
    acc += (float)agg[(size_t)i * HD + t];
  }
  atomicAdd(&p[curg * HD + t], acc);
  if (t == 0) atomicAdd(&gcnt[curg], (float)(end - runStart));
}

// ---- head
__global__ __launch_bounds__(128) void k_head(const float* __restrict__ p, const float* __restrict__ gcnt,
                                              const float* __restrict__ w3,
                                              const float* __restrict__ c1w, const float* __restrict__ c1b,
                                              const float* __restrict__ c2w, const float* __restrict__ c2b,
                                              const float* __restrict__ c3w, const float* __restrict__ c3b,
                                              float* __restrict__ out) {
  __shared__ float sa[128], sb[128];
  int g = blockIdx.x, t = threadIdx.x;
  float inv = 1.f / fmaxf(gcnt[g], 1.f);
  sa[t] = p[g * HD + t] * inv;
  __syncthreads();
  float z = 0.f;
  for (int k = 0; k < HD; ++k) z += sa[k] * w3[k * HD + t];
  z *= TP_NORM_F;
  out[128 + g * HD + t] = z;
  sb[t] = z;
  __syncthreads();
  float o1 = c1b[t];
  for (int k = 0; k < HD; ++k) o1 += sb[k] * c1w[k * HD + t];
  o1 = fmaxf(o1, 0.f);
  __syncthreads();
  sa[t] = o1;
  __syncthreads();
  float o2 = c2b[t];
  for (int k = 0; k < HD; ++k) o2 += sa[k] * c2w[k * HD + t];
  o2 = fmaxf(o2, 0.f);
  __syncthreads();
  sb[t] = o2;
  __syncthreads();
  if (t < 2) {
    float o = c3b[t];
    for (int k = 0; k < HD; ++k) o += sb[k] * c3w[k * 2 + t];
    out[g * 2 + t] = o;
  }
}

extern "C" void kernel_launch(void* const* d_in, const int* in_sizes, int n_in,
                              void* d_out, int out_size, void* d_ws, size_t ws_size,
                              hipStream_t stream) {
  const float* x = (const float*)d_in[0];
  const int* eidx = (const int*)d_in[2];
  const int* src = eidx;
  const int* dst = eidx + N_EDGES;
  const int* batch = (const int*)d_in[3];
  const float* lin_w = (const float*)d_in[4];
  const float* lin_b = (const float*)d_in[5];
  const float* tp_w1 = (const float*)d_in[6];
  const float* tp_w2 = (const float*)d_in[7];
  const float* tp_w3 = (const float*)d_in[8];
  const float* c1w = (const float*)d_in[9];
  const float* c1b = (const float*)d_in[10];
  const float* c2w = (const float*)d_in[11];
  const float* c2b = (const float*)d_in[12];
  const float* c3w = (const float*)d_in[13];
  const float* c3b = (const float*)d_in[14];
  float* out = (float*)d_out;
  (void)in_sizes; (void)n_in; (void)out_size; (void)ws_size;

  uintptr_t wp = (uintptr_t)d_ws;
  auto alloc = [&](size_t bytes) -> void* {
    uintptr_t a = (wp + 255) & ~(uintptr_t)255;
    wp = a + bytes;
    return (void*)a;
  };
  bf16_t* WtL  = (bf16_t*)alloc(sizeof(bf16_t) * (size_t)HD * FIN);
  bf16_t* Wt1  = (bf16_t*)alloc(sizeof(bf16_t) * (size_t)HD * HD);
  bf16_t* Wt2  = (bf16_t*)alloc(sizeof(bf16_t) * (size_t)HD * HD);
  bf16_t* h    = (bf16_t*)alloc(sizeof(bf16_t) * (size_t)50048 * HD);
  bf16_t* agg  = (bf16_t*)alloc(sizeof(bf16_t) * (size_t)50048 * HD);
  int*    bcnt = (int*)alloc(sizeof(int) * NBUCK);
  int*    boff = (int*)alloc(sizeof(int) * (NBUCK + 1));
  int*    bsumA= (int*)alloc(sizeof(int) * 9600);   // 9571 + total
  int*    bsumB= (int*)alloc(sizeof(int) * 300);    // 38 + total
  int*    boffA= (int*)alloc(sizeof(int) * 9600);
  int*    pos  = (int*)alloc(sizeof(int) * N_EDGES);
  int*    ssrc = (int*)alloc(sizeof(int) * N_EDGES);
  float*  pbuf = (float*)alloc(sizeof(float) * NG * HD);
  float*  gcnt = (float*)alloc(sizeof(float) * NG);

  hipMemsetAsync(bcnt, 0, sizeof(int) * NBUCK, stream);

  const int edgeBlocks = (N_EDGES + 255) / 256;  // 6250
  k_prep_hist<<<768 + edgeBlocks, 256, 0, stream>>>(lin_w, tp_w1, tp_w2, WtL, Wt1, Wt2,
                                                    pbuf, gcnt, src, dst, bcnt, pos);

  // 3-level exclusive scan of bcnt[2,450,000] -> boff
  const int L1 = (NBUCK + 255) / 256;  // 9571
  const int L2 = (L1 + 255) / 256;     // 38
  k_scan1<<<L1, 256, 0, stream>>>(bcnt, bsumA, NBUCK);
  k_scan1<<<L2, 256, 0, stream>>>(bsumA, bsumB, L1);
  k_scan2<<<1, 256, 0, stream>>>(bsumB, L2);
  k_scan3<<<L2, 256, 0, stream>>>(bsumA, bsumB, boffA, L1);
  k_scan3<<<L1, 256, 0, stream>>>(bcnt, boffA, boff, NBUCK);

  const int gblocks = (N_NODES + 31) / 32;   // 1563
  // packed: h0 = relu(x @ lin_w + b)  ||  ssrc bucket scatter
  k_lin_fill<<<gblocks + edgeBlocks, 256, 0, stream>>>(x, WtL, lin_b, h, src, dst, boff, pos, ssrc);

  // conv1, conv2 fused (aggregate->LDS->GEMM), ping-pong h/agg
  k_conv_fused<<<gblocks, 256, 0, stream>>>(h, ssrc, boff, Wt1, agg, N_NODES);
  k_conv_fused<<<gblocks, 256, 0, stream>>>(agg, ssrc, boff, Wt2, h, N_NODES);
  // conv3 aggregation only (W3 folded into head)
  k_aggregate<<<(N_NODES + 3) / 4, 256, 0, stream>>>(h, ssrc, boff, agg, N_NODES);

  k_pool<<<(N_NODES + 63) / 64, 128, 0, stream>>>(agg, batch, pbuf, gcnt, N_NODES);
  k_head<<<NG, 128, 0, stream>>>(pbuf, gcnt, tp_w3, c1w, c1b, c2w, c2b, c3w, c3b, out);
}